// Round 11
// baseline (69.777 us; speedup 1.0000x reference)
//
#include <hip/hip_runtime.h>
#include <hip/hip_bf16.h>

#ifndef __has_builtin
#define __has_builtin(x) 0
#endif

__device__ __forceinline__ float fast_exp2(float x) {
#if __has_builtin(__builtin_amdgcn_exp2f)
  return __builtin_amdgcn_exp2f(x);
#else
  return __exp2f(x);
#endif
}
__device__ __forceinline__ float fast_rcp(float x) {
#if __has_builtin(__builtin_amdgcn_rcpf)
  return __builtin_amdgcn_rcpf(x);
#else
  return 1.0f / x;
#endif
}

#define B_   16
#define NQ_  256
#define NK_  256
#define D_   256
#define QT   4
#define TANH_SCALE 2.8853900817779268f
#define NEG2LOG2E  (-2.8853900817779268f)   // p = exp(-2*acc) = exp2(acc*this)

// ---------------- projection GEMM ------------------------------------------
// z=0: Eq = exp2(TANH_SCALE*(queries@Wq + b1))  -> eqs[m][n]  (row-major)
// z=1: Ek = exp2(TANH_SCALE*(keys@Wk))          -> ekT[b][n][key] TRANSPOSED
// so attn's per-key loads are lane-coalesced (lane t = key t reads
// ekT[b][d][t]: consecutive lanes, consecutive 4B -> 4 lines/wave-load
// instead of 64 with the row-major layout — the 4x cache-path inflation
// that pinned attn at 50us across R3-R10).
__global__ __launch_bounds__(256) void proj_kernel(
    const float* __restrict__ queries, const float* __restrict__ keys,
    const float* __restrict__ Wq, const float* __restrict__ Wk,
    const float* __restrict__ b1,
    float* __restrict__ eqs, float* __restrict__ ekT)
{
  const int z = blockIdx.z;
  const float* __restrict__ X = z ? keys : queries;
  const float* __restrict__ W = z ? Wk : Wq;
  float* __restrict__ O = z ? ekT : eqs;

  const int m0 = blockIdx.x * 64;
  const int n0 = blockIdx.y * 64;
  const int t  = threadIdx.x;
  const int tx = t & 15, ty = t >> 4;

  __shared__ float As[64][68];   // [m][k], padded
  __shared__ float Bs[64][68];   // [k][n]

  float acc[4][4] = {};

  for (int kt = 0; kt < 4; ++kt) {
    const int k0 = kt * 64;
    #pragma unroll
    for (int i = 0; i < 4; ++i) {          // A tile, direct copy
      int f = t + 256 * i;
      int row = f >> 4;
      int kc  = (f & 15) << 2;
      *(float4*)&As[row][kc] = *(const float4*)&X[(size_t)(m0 + row) * D_ + (k0 + kc)];
    }
    #pragma unroll
    for (int i = 0; i < 4; ++i) {          // B tile
      int f = t + 256 * i;
      int kr = f >> 4;
      int nc = (f & 15) << 2;
      *(float4*)&Bs[kr][nc] = *(const float4*)&W[(size_t)(k0 + kr) * D_ + (n0 + nc)];
    }
    __syncthreads();
    #pragma unroll 4
    for (int k4 = 0; k4 < 16; ++k4) {      // 4 k's per iter
      const int kk = k4 << 2;
      float4 a0 = *(const float4*)&As[(ty << 2) + 0][kk];
      float4 a1 = *(const float4*)&As[(ty << 2) + 1][kk];
      float4 a2 = *(const float4*)&As[(ty << 2) + 2][kk];
      float4 a3 = *(const float4*)&As[(ty << 2) + 3][kk];
      float4 b0 = *(const float4*)&Bs[kk + 0][tx << 2];
      float4 b1v = *(const float4*)&Bs[kk + 1][tx << 2];
      float4 b2 = *(const float4*)&Bs[kk + 2][tx << 2];
      float4 b3 = *(const float4*)&Bs[kk + 3][tx << 2];
      float A[4][4] = {{a0.x,a0.y,a0.z,a0.w},{a1.x,a1.y,a1.z,a1.w},
                       {a2.x,a2.y,a2.z,a2.w},{a3.x,a3.y,a3.z,a3.w}};
      float Bv[4][4] = {{b0.x,b0.y,b0.z,b0.w},{b1v.x,b1v.y,b1v.z,b1v.w},
                        {b2.x,b2.y,b2.z,b2.w},{b3.x,b3.y,b3.z,b3.w}};
      #pragma unroll
      for (int kkk = 0; kkk < 4; ++kkk)
        #pragma unroll
        for (int i = 0; i < 4; ++i)
          #pragma unroll
          for (int j = 0; j < 4; ++j)
            acc[i][j] = fmaf(A[i][kkk], Bv[kkk][j], acc[i][j]);
    }
    __syncthreads();
  }

  if (z == 0) {
    float bias[4];
    #pragma unroll
    for (int j = 0; j < 4; ++j) bias[j] = b1[n0 + (tx << 2) + j];
    #pragma unroll
    for (int i = 0; i < 4; ++i) {
      float4 o4;
      o4.x = fast_exp2(TANH_SCALE * (acc[i][0] + bias[0]));
      o4.y = fast_exp2(TANH_SCALE * (acc[i][1] + bias[1]));
      o4.z = fast_exp2(TANH_SCALE * (acc[i][2] + bias[2]));
      o4.w = fast_exp2(TANH_SCALE * (acc[i][3] + bias[3]));
      *(float4*)&O[(size_t)(m0 + (ty << 2) + i) * D_ + n0 + (tx << 2)] = o4;
    }
  } else {
    // transposed store: ekT[batch][n][key]; float4 along key dim (i)
    const int batch = m0 >> 8;
    const int key0  = (m0 & 255) + (ty << 2);
    #pragma unroll
    for (int j = 0; j < 4; ++j) {
      float4 o4;
      o4.x = fast_exp2(TANH_SCALE * acc[0][j]);
      o4.y = fast_exp2(TANH_SCALE * acc[1][j]);
      o4.z = fast_exp2(TANH_SCALE * acc[2][j]);
      o4.w = fast_exp2(TANH_SCALE * acc[3][j]);
      *(float4*)&O[((size_t)batch << 16) +
                   (size_t)(n0 + (tx << 2) + j) * NK_ + key0] = o4;
    }
  }
}

// ---------------- fused logits + softmax + PV (R10 + coalesced ekT) --------
// Block = (b, 4 queries), 256 threads. Thread t = key t in logits.
// Ek loads now COALESCED via ekT[b][d][key]: lane t reads ekT[d][t] —
// 4 scalar loads per d4, each 4 cachelines/wave (was 1 float4 load touching
// 64 lines). eq/w2 block-uniform -> s_load. Quad-rcp (1 rcp per qi*d4).
// No max pass: |logit| <= 2*sum|w2| ~ 26, exp2-safe (verified R4-R10).
// b = wgid&15 pins 2 batches per XCD -> L2-resident.
__global__ __launch_bounds__(256, 4) void attn_kernel(
    const float* __restrict__ eqs, const float* __restrict__ ekT,
    const float* __restrict__ values, const float* __restrict__ w2,
    float* __restrict__ out)
{
  const int wgid = blockIdx.x;
  const int b  = wgid & 15;
  const int q0 = (wgid >> 4) * QT;
  const int t  = threadIdx.x;
  const int lane = t & 63, wave = t >> 6;

  __shared__ float pvred[4][QT][D_];          // 16KB
  __shared__ float redB[4][QT];

  const float* __restrict__ ekTb  = ekT + ((size_t)b << 16);            // [d][key]
  const float* __restrict__ equni = eqs + ((size_t)(b * NQ_) + q0) * D_; // uniform

  float acc[QT] = {};
  #pragma unroll 4
  for (int d4 = 0; d4 < D_ / 4; ++d4) {
    const int off = d4 << 2;
    float e0 = ekTb[(size_t)(off + 0) * NK_ + t];   // coalesced: lane = key
    float e1 = ekTb[(size_t)(off + 1) * NK_ + t];
    float e2 = ekTb[(size_t)(off + 2) * NK_ + t];
    float e3 = ekTb[(size_t)(off + 3) * NK_ + t];
    float4 wv = *(const float4*)&w2[off];           // uniform -> s_load
    float w[4] = {wv.x, wv.y, wv.z, wv.w};
    #pragma unroll
    for (int qi = 0; qi < QT; ++qi) {
      float4 eqv = *(const float4*)&equni[(size_t)qi * D_ + off];  // uniform
      float t0 = fmaf(eqv.x, e0, 1.0f);
      float t1 = fmaf(eqv.y, e1, 1.0f);
      float t2 = fmaf(eqv.z, e2, 1.0f);
      float t3 = fmaf(eqv.w, e3, 1.0f);
      float p01 = t0 * t1;
      float p23 = t2 * t3;
      float n01 = fmaf(w[1], t0, w[0] * t1);
      float n23 = fmaf(w[3], t2, w[2] * t3);
      float num = fmaf(n23, p01, n01 * p23);
      float r   = fast_rcp(p01 * p23);
      acc[qi] = fmaf(num, r, acc[qi]);
    }
  }

  // ---- no-max softmax: p = exp2(-2*log2e*acc), block-wide denominator ----
  float p[QT];
  #pragma unroll
  for (int qi = 0; qi < QT; ++qi)
    p[qi] = fast_exp2(NEG2LOG2E * acc[qi]);
  #pragma unroll
  for (int qi = 0; qi < QT; ++qi) {
    float v = p[qi];
    #pragma unroll
    for (int off = 32; off; off >>= 1) v += __shfl_xor(v, off, 64);
    if (lane == 0) redB[wave][qi] = v;
  }
  __syncthreads();
  float pl[QT];
  #pragma unroll
  for (int qi = 0; qi < QT; ++qi) {
    float inv = fast_rcp(redB[0][qi] + redB[1][qi] + redB[2][qi] + redB[3][qi]);
    pl[qi] = p[qi] * inv;   // normalized weight for this thread's key
  }

  // ---- PV: wave-local over its 64 keys, p broadcast via readlane ----
  // (values reads already coalesced: lanes = consecutive 16B within a row)
  float ctx[QT][4] = {};
  const float* __restrict__ vbase =
      values + ((size_t)(b * NK_) + (wave << 6)) * D_ + (lane << 2);
  #pragma unroll 4
  for (int kl = 0; kl < 64; ++kl) {
    float4 vv = *(const float4*)&vbase[(size_t)kl * D_];
    float vz[4] = {vv.x, vv.y, vv.z, vv.w};
    #pragma unroll
    for (int qi = 0; qi < QT; ++qi) {
      float pk = __int_as_float(
          __builtin_amdgcn_readlane(__float_as_int(pl[qi]), kl));
      #pragma unroll
      for (int j = 0; j < 4; ++j)
        ctx[qi][j] = fmaf(pk, vz[j], ctx[qi][j]);
    }
  }

  // ---- combine 4 waves' partials via LDS ----
  #pragma unroll
  for (int qi = 0; qi < QT; ++qi)
    *(float4*)&pvred[wave][qi][lane << 2] =
        make_float4(ctx[qi][0], ctx[qi][1], ctx[qi][2], ctx[qi][3]);
  __syncthreads();
  #pragma unroll
  for (int qi = 0; qi < QT; ++qi) {
    float o = pvred[0][qi][t] + pvred[1][qi][t] +
              pvred[2][qi][t] + pvred[3][qi][t];
    out[((size_t)(b * NQ_) + q0 + qi) * D_ + t] = o;
  }
}

extern "C" void kernel_launch(void* const* d_in, const int* in_sizes, int n_in,
                              void* d_out, int out_size, void* d_ws, size_t ws_size,
                              hipStream_t stream)
{
  const float* keys    = (const float*)d_in[0];
  const float* queries = (const float*)d_in[1];
  const float* values  = (const float*)d_in[2];
  const float* Wk      = (const float*)d_in[3];
  const float* Wq      = (const float*)d_in[4];
  const float* b1      = (const float*)d_in[5];
  const float* w2      = (const float*)d_in[6];
  // d_in[7] = b2: dropped (softmax shift-invariance)

  float* eqs = (float*)d_ws;                       // [4096,256] f32, 4 MB
  float* ekT = eqs + (size_t)B_ * NQ_ * D_;        // [16][256][256] f32, 4 MB
  float* out = (float*)d_out;

  dim3 pgrid(B_ * NQ_ / 64, D_ / 64, 2);           // 64 x 4 x 2 = 512 blocks
  proj_kernel<<<pgrid, 256, 0, stream>>>(queries, keys, Wq, Wk, b1, eqs, ekT);

  attn_kernel<<<dim3(B_ * NQ_ / QT), 256, 0, stream>>>(eqs, ekT, values, w2, out);
}

// Round 12
// 69.752 us; speedup vs baseline: 1.0004x; 1.0004x over previous
//
#include <hip/hip_runtime.h>
#include <hip/hip_bf16.h>

#ifndef __has_builtin
#define __has_builtin(x) 0
#endif

__device__ __forceinline__ float fast_exp2(float x) {
#if __has_builtin(__builtin_amdgcn_exp2f)
  return __builtin_amdgcn_exp2f(x);
#else
  return __exp2f(x);
#endif
}
__device__ __forceinline__ float fast_rcp(float x) {
#if __has_builtin(__builtin_amdgcn_rcpf)
  return __builtin_amdgcn_rcpf(x);
#else
  return 1.0f / x;
#endif
}

#define B_   16
#define NQ_  256
#define NK_  256
#define D_   256
#define QT   4
#define TANH_SCALE 2.8853900817779268f
#define NEG2LOG2E  (-2.8853900817779268f)   // p = exp(-2*acc) = exp2(acc*this)

// ---------------- projection GEMM ------------------------------------------
// z=0: Eq = exp2(TANH_SCALE*(queries@Wq + b1))  -> eqs[m][n]
// z=1: Ek = exp2(TANH_SCALE*(keys@Wk)); layout row-major (tr=0, fallback) or
//      ekT[b][n][key] transposed (tr=1, coalesced attn loads).
__global__ __launch_bounds__(256) void proj_kernel(
    const float* __restrict__ queries, const float* __restrict__ keys,
    const float* __restrict__ Wq, const float* __restrict__ Wk,
    const float* __restrict__ b1,
    float* __restrict__ eqs, float* __restrict__ ek_out, int tr)
{
  const int z = blockIdx.z;
  const float* __restrict__ X = z ? keys : queries;
  const float* __restrict__ W = z ? Wk : Wq;
  float* __restrict__ O = z ? ek_out : eqs;

  const int m0 = blockIdx.x * 64;
  const int n0 = blockIdx.y * 64;
  const int t  = threadIdx.x;
  const int tx = t & 15, ty = t >> 4;

  __shared__ float As[64][68];   // [m][k], padded
  __shared__ float Bs[64][68];   // [k][n]

  float acc[4][4] = {};

  for (int kt = 0; kt < 4; ++kt) {
    const int k0 = kt * 64;
    #pragma unroll
    for (int i = 0; i < 4; ++i) {          // A tile, direct copy
      int f = t + 256 * i;
      int row = f >> 4;
      int kc  = (f & 15) << 2;
      *(float4*)&As[row][kc] = *(const float4*)&X[(size_t)(m0 + row) * D_ + (k0 + kc)];
    }
    #pragma unroll
    for (int i = 0; i < 4; ++i) {          // B tile
      int f = t + 256 * i;
      int kr = f >> 4;
      int nc = (f & 15) << 2;
      *(float4*)&Bs[kr][nc] = *(const float4*)&W[(size_t)(k0 + kr) * D_ + (n0 + nc)];
    }
    __syncthreads();
    #pragma unroll 4
    for (int k4 = 0; k4 < 16; ++k4) {      // 4 k's per iter
      const int kk = k4 << 2;
      float4 a0 = *(const float4*)&As[(ty << 2) + 0][kk];
      float4 a1 = *(const float4*)&As[(ty << 2) + 1][kk];
      float4 a2 = *(const float4*)&As[(ty << 2) + 2][kk];
      float4 a3 = *(const float4*)&As[(ty << 2) + 3][kk];
      float4 b0 = *(const float4*)&Bs[kk + 0][tx << 2];
      float4 b1v = *(const float4*)&Bs[kk + 1][tx << 2];
      float4 b2 = *(const float4*)&Bs[kk + 2][tx << 2];
      float4 b3 = *(const float4*)&Bs[kk + 3][tx << 2];
      float A[4][4] = {{a0.x,a0.y,a0.z,a0.w},{a1.x,a1.y,a1.z,a1.w},
                       {a2.x,a2.y,a2.z,a2.w},{a3.x,a3.y,a3.z,a3.w}};
      float Bv[4][4] = {{b0.x,b0.y,b0.z,b0.w},{b1v.x,b1v.y,b1v.z,b1v.w},
                        {b2.x,b2.y,b2.z,b2.w},{b3.x,b3.y,b3.z,b3.w}};
      #pragma unroll
      for (int kkk = 0; kkk < 4; ++kkk)
        #pragma unroll
        for (int i = 0; i < 4; ++i)
          #pragma unroll
          for (int j = 0; j < 4; ++j)
            acc[i][j] = fmaf(A[i][kkk], Bv[kkk][j], acc[i][j]);
    }
    __syncthreads();
  }

  if (z == 0) {
    float bias[4];
    #pragma unroll
    for (int j = 0; j < 4; ++j) bias[j] = b1[n0 + (tx << 2) + j];
    #pragma unroll
    for (int i = 0; i < 4; ++i) {
      float4 o4;
      o4.x = fast_exp2(TANH_SCALE * (acc[i][0] + bias[0]));
      o4.y = fast_exp2(TANH_SCALE * (acc[i][1] + bias[1]));
      o4.z = fast_exp2(TANH_SCALE * (acc[i][2] + bias[2]));
      o4.w = fast_exp2(TANH_SCALE * (acc[i][3] + bias[3]));
      *(float4*)&O[(size_t)(m0 + (ty << 2) + i) * D_ + n0 + (tx << 2)] = o4;
    }
  } else if (tr) {
    // transposed store: ekT[batch][n][key]; float4 along key dim
    const int batch = m0 >> 8;
    const int key0  = (m0 & 255) + (ty << 2);
    #pragma unroll
    for (int j = 0; j < 4; ++j) {
      float4 o4;
      o4.x = fast_exp2(TANH_SCALE * acc[0][j]);
      o4.y = fast_exp2(TANH_SCALE * acc[1][j]);
      o4.z = fast_exp2(TANH_SCALE * acc[2][j]);
      o4.w = fast_exp2(TANH_SCALE * acc[3][j]);
      *(float4*)&O[((size_t)batch << 16) +
                   (size_t)(n0 + (tx << 2) + j) * NK_ + key0] = o4;
    }
  } else {
    #pragma unroll
    for (int i = 0; i < 4; ++i) {
      float4 o4;
      o4.x = fast_exp2(TANH_SCALE * acc[i][0]);
      o4.y = fast_exp2(TANH_SCALE * acc[i][1]);
      o4.z = fast_exp2(TANH_SCALE * acc[i][2]);
      o4.w = fast_exp2(TANH_SCALE * acc[i][3]);
      *(float4*)&O[(size_t)(m0 + (ty << 2) + i) * D_ + n0 + (tx << 2)] = o4;
    }
  }
}

// ---------------- wave64 flash attention ------------------------------------
// ONE WAVE per workgroup; zero barriers, zero LDS. Grid 4096 = kh(4) x qq(64)
// x b(16). Wave = (b, 4 queries, 64 keys); lane = key. ek loads coalesced via
// ekT; eq/w2 block-uniform -> s_load; softmax denom = pure shfl_xor; PV via
// readlane. Tests the ONE untested axis: block granularity / lockstep-cohort
// scheduling (R3-R11 all 256-thr serial-phase blocks, all ~50us).
// Quad-rcp + no-max softmax (validated R4-R11).
__global__ __launch_bounds__(64) void attn_wave(
    const float* __restrict__ eqs, const float* __restrict__ ekT,
    const float* __restrict__ values, const float* __restrict__ w2,
    float* __restrict__ sctx, float* __restrict__ psum)
{
  const int wgid = blockIdx.x;
  const int b    = wgid & 15;
  const int qq   = (wgid >> 4) & 63;
  const int kh   = wgid >> 10;
  const int q0   = qq * QT;
  const int k0   = kh * 64;
  const int lane = threadIdx.x;

  const float* __restrict__ ekTb  = ekT + ((size_t)b << 16);             // [d][key]
  const float* __restrict__ equni = eqs + ((size_t)(b * NQ_) + q0) * D_; // uniform

  // ---- logits: lane = key k0+lane, full D loop ----
  float acc[QT] = {};
  #pragma unroll 4
  for (int d4 = 0; d4 < D_ / 4; ++d4) {
    const int off = d4 << 2;
    const float* ekp = &ekTb[(size_t)off * NK_ + k0 + lane];
    float e0 = ekp[0 * NK_];          // coalesced: 64 consecutive floats
    float e1 = ekp[1 * NK_];
    float e2 = ekp[2 * NK_];
    float e3 = ekp[3 * NK_];
    float4 wv = *(const float4*)&w2[off];                  // s_load
    float w[4] = {wv.x, wv.y, wv.z, wv.w};
    #pragma unroll
    for (int qi = 0; qi < QT; ++qi) {
      float4 eqv = *(const float4*)&equni[(size_t)qi * D_ + off];  // s_load
      float t0 = fmaf(eqv.x, e0, 1.0f);
      float t1 = fmaf(eqv.y, e1, 1.0f);
      float t2 = fmaf(eqv.z, e2, 1.0f);
      float t3 = fmaf(eqv.w, e3, 1.0f);
      float p01 = t0 * t1;
      float p23 = t2 * t3;
      float n01 = fmaf(w[1], t0, w[0] * t1);
      float n23 = fmaf(w[3], t2, w[2] * t3);
      float num = fmaf(n23, p01, n01 * p23);
      acc[qi] = fmaf(num, fast_rcp(p01 * p23), acc[qi]);
    }
  }

  // ---- unnormalized p + wave-local partial denominator (shfl only) ----
  float p[QT], s[QT];
  #pragma unroll
  for (int qi = 0; qi < QT; ++qi) {
    p[qi] = fast_exp2(NEG2LOG2E * acc[qi]);
    float v = p[qi];
    #pragma unroll
    for (int off = 32; off; off >>= 1) v += __shfl_xor(v, off, 64);
    s[qi] = v;
  }
  if (lane == 0)
    *(float4*)&psum[(size_t)wgid * 4] = make_float4(s[0], s[1], s[2], s[3]);

  // ---- PV over this wave's 64 keys; lane = 4 value dims ----
  float ctx[QT][4] = {};
  const float* __restrict__ vbase =
      values + ((size_t)(b * NK_) + k0) * D_ + (lane << 2);
  #pragma unroll 4
  for (int i = 0; i < 64; ++i) {
    float4 vv = *(const float4*)&vbase[(size_t)i * D_];
    float vz[4] = {vv.x, vv.y, vv.z, vv.w};
    #pragma unroll
    for (int qi = 0; qi < QT; ++qi) {
      float pk = __int_as_float(
          __builtin_amdgcn_readlane(__float_as_int(p[qi]), i));
      #pragma unroll
      for (int j = 0; j < 4; ++j)
        ctx[qi][j] = fmaf(pk, vz[j], ctx[qi][j]);
    }
  }
  #pragma unroll
  for (int qi = 0; qi < QT; ++qi)
    *(float4*)&sctx[((size_t)wgid * 4 + qi) * D_ + (lane << 2)] =
        make_float4(ctx[qi][0], ctx[qi][1], ctx[qi][2], ctx[qi][3]);
}

// ---------------- combine: sum 4 key-quarters + normalize -------------------
__global__ __launch_bounds__(256) void combine_kernel(
    const float* __restrict__ sctx, const float* __restrict__ psum,
    float* __restrict__ out)
{
  const int bid = blockIdx.x;     // 1024 = qq*16 + b
  const int b = bid & 15, qq = bid >> 4;
  const int t = threadIdx.x;

  #pragma unroll
  for (int qi = 0; qi < QT; ++qi) {
    float s = 0.f, o = 0.f;
    #pragma unroll
    for (int kh = 0; kh < 4; ++kh) {
      const size_t wg = (size_t)(kh * 1024 + bid);
      s += psum[wg * 4 + qi];
      o += sctx[(wg * 4 + qi) * D_ + t];
    }
    out[((size_t)(b * NQ_) + qq * QT + qi) * D_ + t] = o * fast_rcp(s);
  }
}

// ---------------- fallback (R10 kernel, passed): used if ws too small -------
__global__ __launch_bounds__(256, 4) void attn_fallback(
    const float* __restrict__ eqs, const float* __restrict__ eks,
    const float* __restrict__ values, const float* __restrict__ w2,
    float* __restrict__ out)
{
  const int wgid = blockIdx.x;
  const int b  = wgid & 15;
  const int q0 = (wgid >> 4) * QT;
  const int t  = threadIdx.x;
  const int lane = t & 63, wave = t >> 6;

  __shared__ float pvred[4][QT][D_];
  __shared__ float redB[4][QT];

  const float* __restrict__ ekrow = eks + ((size_t)(b * NK_) + t) * D_;
  const float* __restrict__ equni = eqs + ((size_t)(b * NQ_) + q0) * D_;

  float acc[QT] = {};
  #pragma unroll 4
  for (int d4 = 0; d4 < D_ / 4; ++d4) {
    const int off = d4 << 2;
    float4 ekv = *(const float4*)&ekrow[off];
    float4 wv  = *(const float4*)&w2[off];
    float e[4] = {ekv.x, ekv.y, ekv.z, ekv.w};
    float w[4] = {wv.x, wv.y, wv.z, wv.w};
    #pragma unroll
    for (int qi = 0; qi < QT; ++qi) {
      float4 eqv = *(const float4*)&equni[(size_t)qi * D_ + off];
      float t0 = fmaf(eqv.x, e[0], 1.0f);
      float t1 = fmaf(eqv.y, e[1], 1.0f);
      float t2 = fmaf(eqv.z, e[2], 1.0f);
      float t3 = fmaf(eqv.w, e[3], 1.0f);
      float p01 = t0 * t1;
      float p23 = t2 * t3;
      float n01 = fmaf(w[1], t0, w[0] * t1);
      float n23 = fmaf(w[3], t2, w[2] * t3);
      float num = fmaf(n23, p01, n01 * p23);
      acc[qi] = fmaf(num, fast_rcp(p01 * p23), acc[qi]);
    }
  }

  float p[QT];
  #pragma unroll
  for (int qi = 0; qi < QT; ++qi)
    p[qi] = fast_exp2(NEG2LOG2E * acc[qi]);
  #pragma unroll
  for (int qi = 0; qi < QT; ++qi) {
    float v = p[qi];
    #pragma unroll
    for (int off = 32; off; off >>= 1) v += __shfl_xor(v, off, 64);
    if (lane == 0) redB[wave][qi] = v;
  }
  __syncthreads();
  float pl[QT];
  #pragma unroll
  for (int qi = 0; qi < QT; ++qi) {
    float inv = fast_rcp(redB[0][qi] + redB[1][qi] + redB[2][qi] + redB[3][qi]);
    pl[qi] = p[qi] * inv;
  }

  float ctx[QT][4] = {};
  const float* __restrict__ vbase =
      values + ((size_t)(b * NK_) + (wave << 6)) * D_ + (lane << 2);
  #pragma unroll 4
  for (int kl = 0; kl < 64; ++kl) {
    float4 vv = *(const float4*)&vbase[(size_t)kl * D_];
    float vz[4] = {vv.x, vv.y, vv.z, vv.w};
    #pragma unroll
    for (int qi = 0; qi < QT; ++qi) {
      float pk = __int_as_float(
          __builtin_amdgcn_readlane(__float_as_int(pl[qi]), kl));
      #pragma unroll
      for (int j = 0; j < 4; ++j)
        ctx[qi][j] = fmaf(pk, vz[j], ctx[qi][j]);
    }
  }

  #pragma unroll
  for (int qi = 0; qi < QT; ++qi)
    *(float4*)&pvred[wave][qi][lane << 2] =
        make_float4(ctx[qi][0], ctx[qi][1], ctx[qi][2], ctx[qi][3]);
  __syncthreads();
  #pragma unroll
  for (int qi = 0; qi < QT; ++qi) {
    float o = pvred[0][qi][t] + pvred[1][qi][t] +
              pvred[2][qi][t] + pvred[3][qi][t];
    out[((size_t)(b * NQ_) + q0 + qi) * D_ + t] = o;
  }
}

extern "C" void kernel_launch(void* const* d_in, const int* in_sizes, int n_in,
                              void* d_out, int out_size, void* d_ws, size_t ws_size,
                              hipStream_t stream)
{
  const float* keys    = (const float*)d_in[0];
  const float* queries = (const float*)d_in[1];
  const float* values  = (const float*)d_in[2];
  const float* Wk      = (const float*)d_in[3];
  const float* Wq      = (const float*)d_in[4];
  const float* b1      = (const float*)d_in[5];
  const float* w2      = (const float*)d_in[6];
  // d_in[7] = b2: dropped (softmax shift-invariance)

  float* eqs  = (float*)d_ws;                      // 4 MB
  float* ekb  = eqs + (size_t)B_ * NQ_ * D_;       // 4 MB (ekT or eks)
  float* sctx = ekb + (size_t)B_ * NK_ * D_;       // [4096][4][256] = 16 MB
  float* psum = sctx + (size_t)4096 * 4 * 256;     // [4096][4] = 64 KB
  float* out  = (float*)d_out;

  const size_t need = ((size_t)2 * B_ * NQ_ * D_ + (size_t)4096 * 4 * 256 +
                       (size_t)4096 * 4) * sizeof(float);   // ~24.1 MB
  const int use_wave = (ws_size >= need) ? 1 : 0;

  dim3 pgrid(B_ * NQ_ / 64, D_ / 64, 2);           // 64 x 4 x 2 = 512 blocks
  proj_kernel<<<pgrid, 256, 0, stream>>>(queries, keys, Wq, Wk, b1,
                                         eqs, ekb, use_wave);

  if (use_wave) {
    attn_wave<<<dim3(4096), 64, 0, stream>>>(eqs, ekb, values, w2, sctx, psum);
    combine_kernel<<<dim3(1024), 256, 0, stream>>>(sctx, psum, out);
  } else {
    attn_fallback<<<dim3(B_ * NQ_ / QT), 256, 0, stream>>>(eqs, ekb, values, w2, out);
  }
}